// Round 8
// baseline (289.112 us; speedup 1.0000x reference)
//
#include <hip/hip_runtime.h>
#include <cstdint>
#include <cstddef>

#define FMIN_F (-3.402823466e38f)

__device__ __forceinline__ float wave_sum(float v) {
#pragma unroll
    for (int off = 32; off > 0; off >>= 1)
        v += __shfl_down(v, off, 64);
    return v; // valid in lane 0
}

// ---------------- GEMV: X-slice in LDS, pure W streaming ----------------
// R7 post-mortem: compiler allocated VGPR=60 (< the 96 needed) and
// re-sequenced "independent" loads into load-use pairs -> ~2KB in
// flight/wave -> 2.5 TB/s. This shape targets the proven streaming regime
// (m146 RMSNorm: 4.9 TB/s): 16 waves/CU, 8 independent 16B loads per row,
// X read from LDS (staged once, single barrier), acc+w <= ~90 VGPR.
// Block: (mat, 16 rows, K-slice of 2048 floats). Wave: 4 rows.
// part layout: [mat][slice(2)][batch(4)][4096]
template <int NMAT>
__global__ __launch_bounds__(256, 4) void gemv_fused_kernel(
    const float* __restrict__ X,                                  // [4][4096]
    const float* __restrict__ W0, const float* __restrict__ W1,
    const float* __restrict__ W2,
    float* __restrict__ part)
{
    __shared__ float4 sX[4][512];                     // 32 KB X-slice
    const int tid = threadIdx.x;
    int bid = blockIdx.x;
    const int mi    = (NMAT == 1) ? 0 : (bid >> 9);   // /512 blocks per mat
    const int rem   = (NMAT == 1) ? bid : (bid & 511);
    const int slice = rem & 1;
    const int r0    = (rem >> 1) * 16;                // 16 rows per block
    const int ko    = slice * 512;                    // float4 offset of slice

    const float4* X4 = (const float4*)X;
    for (int i = tid; i < 2048; i += 256) {
        const int b = i >> 9, j = i & 511;
        sX[b][j] = X4[b * 1024 + ko + j];
    }
    __syncthreads();                                  // the only barrier

    const int wave = tid >> 6;
    const int lane = tid & 63;
    const float* W = (mi == 0) ? W0 : (mi == 1) ? W1 : W2;
    const float4* W4 = (const float4*)W;
    const int rbase = r0 + wave * 4;

    float acc[4][4];
#pragma unroll
    for (int r = 0; r < 4; ++r)
#pragma unroll
        for (int b = 0; b < 4; ++b) acc[r][b] = 0.f;

#pragma unroll
    for (int row = 0; row < 4; ++row) {
        const float4* Wr = W4 + (size_t)(rbase + row) * 1024 + ko;
        float4 w[8];                                  // 8 independent loads
#pragma unroll
        for (int u = 0; u < 8; ++u) w[u] = Wr[u * 64 + lane];
#pragma unroll
        for (int u = 0; u < 8; ++u) {
#pragma unroll
            for (int b = 0; b < 4; ++b) {
                const float4 x = sX[b][u * 64 + lane];
                acc[row][b] += w[u].x * x.x + w[u].y * x.y
                             + w[u].z * x.z + w[u].w * x.w;
            }
        }
    }

#pragma unroll
    for (int row = 0; row < 4; ++row)
#pragma unroll
        for (int b = 0; b < 4; ++b) {
            float v = wave_sum(acc[row][b]);
            if (lane == 0)
                part[(((size_t)mi * 2 + slice) * 4 + b) * 4096 + (rbase + row)] = v;
        }
}

// Sum 2 K-slice partials + bias (+scale for matrix 0)
__global__ __launch_bounds__(256) void gemv_reduce_kernel(
    const float* __restrict__ part,
    const float* __restrict__ B0, const float* __restrict__ B1,
    const float* __restrict__ B2,
    float scale0,
    float* __restrict__ Y)                             // [nmat*4][4096]
{
    const int idx = blockIdx.x * 256 + threadIdx.x;
    const int mi = idx >> 14;
    const int b  = (idx >> 12) & 3;
    const int r  = idx & 4095;
    float s = part[(((size_t)mi * 2 + 0) * 4 + b) * 4096 + r]
            + part[(((size_t)mi * 2 + 1) * 4 + b) * 4096 + r];
    const float* Bs = (mi == 0) ? B0 : (mi == 1) ? B1 : B2;
    s += Bs[r];
    if (mi == 0) s *= scale0;
    Y[((size_t)(mi * 4 + b)) * 4096 + r] = s;
}

// ---------------- Attention phase 1: scores ----------------
__global__ __launch_bounds__(256) void score_kernel(
    const float* __restrict__ qkv,     // [3][4][4096]
    const float* __restrict__ pk,      // [B,H,2048,128]
    const float* __restrict__ amask,   // [B,1,1,2049]
    const float* __restrict__ cam,     // [B*H,1,2049]
    const int* __restrict__ sbp, const int* __restrict__ rbp,
    float* __restrict__ scores)        // [128][512]
{
    constexpr int PAST = 2048, S = 2049, HD = 128;
    const int bh = blockIdx.y;
    const int b  = bh >> 5;
    const int h  = bh & 31;
    const int SB = sbp[0], RB = rbp[0];
    const int NS = SB + 1;
    const int NA = NS + RB + 1;

    const int wave = threadIdx.x >> 6;
    const int lane = threadIdx.x & 63;

    const float* qh   = qkv + (size_t)b * 4096 + h * HD;
    const float* knew = qkv + (size_t)(4 + b) * 4096 + h * HD;
    const float2 ql = ((const float2*)qh)[lane];

#pragma unroll
    for (int j = 0; j < 8; ++j) {
        const int i = blockIdx.x * 32 + j * 4 + wave;
        if (i >= NA) continue;
        const int s = (i < NS) ? i : (PAST - RB + (i - NS));
        const float2* kr = (s < PAST)
            ? (const float2*)(pk + ((size_t)bh * PAST + s) * HD)
            : (const float2*)knew;
        const float2 kk = kr[lane];
        float p = ql.x * kk.x + ql.y * kk.y;
        p = wave_sum(p);
        if (lane == 0) {
            const float m  = cam[(size_t)bh * S + s];
            float sc = fmaxf(p + amask[(size_t)b * S + s], FMIN_F);
            sc = sc * m + (1.0f - m) * FMIN_F;
            scores[(size_t)bh * 512 + i] = sc;
        }
    }
}

// ---------------- Attention phase 2: softmax + coefficient fixups ----------------
__global__ __launch_bounds__(256) void softmax_kernel(
    const float* __restrict__ ps,      // [B*H,2048]
    const int* __restrict__ sbp, const int* __restrict__ rbp,
    float* __restrict__ scores)        // [128][512] in/out
{
    constexpr int PAST = 2048;
    const int bh = blockIdx.x;
    const int SB = sbp[0], RB = rbp[0];
    const int NS = SB + 1;
    const int NA = NS + RB + 1;
    const int tid = threadIdx.x;

    __shared__ float s_c[512];
    __shared__ float s_red[256];
    __shared__ float s_mm;

    for (int i = tid; i < NA; i += 256) s_c[i] = scores[(size_t)bh * 512 + i];

    {
        float part = 0.0f;
        const int cnt = SB + RB;
        for (int i = tid; i < cnt; i += 256) {
            const int idx = (i < SB) ? i : (PAST - RB + (i - SB));
            part += ps[(size_t)bh * PAST + idx];
        }
        s_red[tid] = part;
    }
    __syncthreads();
#pragma unroll
    for (int st = 128; st > 0; st >>= 1) {
        if (tid < st) s_red[tid] += s_red[tid + st];
        __syncthreads();
    }
    if (tid == 0) {
        const float mean = s_red[0] / (float)(SB + RB);
        const float prob = ps[(size_t)bh * PAST + (PAST - RB)] / mean;
        s_mm = (prob > 1.0f) ? (1.0f / 32.0f) : 0.0f;
    }
    __syncthreads();

    float mx = -INFINITY;
    for (int i = tid; i < NA; i += 256) mx = fmaxf(mx, s_c[i]);
    s_red[tid] = mx;
    __syncthreads();
#pragma unroll
    for (int st = 128; st > 0; st >>= 1) {
        if (tid < st) s_red[tid] = fmaxf(s_red[tid], s_red[tid + st]);
        __syncthreads();
    }
    const float gmax = s_red[0];
    __syncthreads();

    float lsum = 0.0f;
    for (int i = tid; i < NA; i += 256) {
        const float e = expf(s_c[i] - gmax);
        s_c[i] = e;
        lsum += e;
    }
    s_red[tid] = lsum;
    __syncthreads();
#pragma unroll
    for (int st = 128; st > 0; st >>= 1) {
        if (tid < st) s_red[tid] += s_red[tid + st];
        __syncthreads();
    }
    const float inv = 1.0f / s_red[0];
    __syncthreads();
    for (int i = tid; i < NA; i += 256) s_c[i] *= inv;
    __syncthreads();

    if (tid == 0) {
        float sm = 0.0f;
#pragma unroll
        for (int j = 1; j <= 32; ++j) sm += s_c[NS + j];
        s_c[NS] += s_mm * sm;       // folded CAM value-merge
        s_c[SB]  = 0.99f;           // pinned col * 0.99 value scale
    }
    __syncthreads();

    for (int i = tid; i < NA; i += 256) scores[(size_t)bh * 512 + i] = s_c[i];
}

// ---------------- Attention phase 3: PV partials ----------------
__global__ __launch_bounds__(256) void pv_kernel(
    const float* __restrict__ qkv,     // for v_new
    const float* __restrict__ pv,      // [B,H,2048,128]
    const float* __restrict__ coeff,   // [128][512]
    const int* __restrict__ sbp, const int* __restrict__ rbp,
    float* __restrict__ partial)       // [128][8][128]
{
    constexpr int PAST = 2048, HD = 128;
    const int bh = blockIdx.y;
    const int b  = bh >> 5;
    const int h  = bh & 31;
    const int SB = sbp[0], RB = rbp[0];
    const int NS = SB + 1;
    const int NA = NS + RB + 1;
    const int CPC = (NA + 7) >> 3;
    const int i0 = blockIdx.x * CPC;
    const int i1 = min(NA, i0 + CPC);

    const int tid  = threadIdx.x;
    const int d    = tid & 127;
    const int half = tid >> 7;

    __shared__ float s_co[64];
    __shared__ float s_red[256];

    if (tid < i1 - i0) s_co[tid] = coeff[(size_t)bh * 512 + i0 + tid];
    __syncthreads();

    const float* vnew = qkv + (size_t)(8 + b) * 4096 + h * HD;

    float acc = 0.0f;
    for (int i = i0 + half; i < i1; i += 2) {
        const int s = (i < NS) ? i : (PAST - RB + (i - NS));
        const float* vr = (s < PAST)
            ? (pv + ((size_t)bh * PAST + s) * HD)
            : vnew;
        acc += s_co[i - i0] * vr[d];
    }
    s_red[tid] = acc;
    __syncthreads();
    if (tid < 128)
        partial[((size_t)bh * 8 + blockIdx.x) * HD + d] = s_red[tid] + s_red[tid + 128];
}

// ---------------- Attention phase 4: reduce partials ----------------
__global__ __launch_bounds__(256) void attn_reduce_kernel(
    const float* __restrict__ partial,  // [128][8][128]
    float* __restrict__ attn_out)       // [4][4096] == [128][128]
{
    const int idx = blockIdx.x * 256 + threadIdx.x;
    const int bh = idx >> 7;
    const int d  = idx & 127;
    float s = 0.0f;
#pragma unroll
    for (int c = 0; c < 8; ++c)
        s += partial[(size_t)bh * 1024 + c * 128 + d];
    attn_out[idx] = s;
}

extern "C" void kernel_launch(void* const* d_in, const int* in_sizes, int n_in,
                              void* d_out, int out_size, void* d_ws, size_t ws_size,
                              hipStream_t stream)
{
    const float* hs = (const float*)d_in[0];
    const float* pk = (const float*)d_in[1];
    const float* pv = (const float*)d_in[2];
    const float* am = (const float*)d_in[3];
    const float* cm = (const float*)d_in[4];
    const float* ps = (const float*)d_in[5];
    const float* Wq = (const float*)d_in[6];
    const float* bq = (const float*)d_in[7];
    const float* Wk = (const float*)d_in[8];
    const float* bk = (const float*)d_in[9];
    const float* Wv = (const float*)d_in[10];
    const float* bv = (const float*)d_in[11];
    const float* Wo = (const float*)d_in[12];
    const float* bo = (const float*)d_in[13];
    const int*   sb = (const int*)d_in[14];
    const int*   rb = (const int*)d_in[15];

    float* qkv   = (float*)d_ws;                   // 49152
    float* aout  = qkv + 3 * 4 * 4096;             // 16384
    float* sc    = aout + 4 * 4096;                // 65536
    float* part  = sc + 128 * 512;                 // 131072
    float* gpart = part + 128 * 8 * 128;           // 3*2*4*4096 = 98304
    float* out   = (float*)d_out;

    const float scaling = 0.08838834764831845f;    // 128^-0.5

    gemv_fused_kernel<3><<<1536, 256, 0, stream>>>(hs, Wq, Wk, Wv, gpart);
    gemv_reduce_kernel<<<192, 256, 0, stream>>>(gpart, bq, bk, bv, scaling, qkv);

    score_kernel<<<dim3(16, 128), 256, 0, stream>>>(qkv, pk, am, cm, sb, rb, sc);
    softmax_kernel<<<128, 256, 0, stream>>>(ps, sb, rb, sc);
    pv_kernel<<<dim3(8, 128), 256, 0, stream>>>(qkv, pv, sc, sb, rb, part);
    attn_reduce_kernel<<<64, 256, 0, stream>>>(part, aout);

    gemv_fused_kernel<1><<<512, 256, 0, stream>>>(aout, Wo, Wo, Wo, gpart);
    gemv_reduce_kernel<<<64, 256, 0, stream>>>(gpart, bo, bo, bo, 1.0f, out);
}

// Round 9
// 90.904 us; speedup vs baseline: 3.1804x; 3.1804x over previous
//
#include <hip/hip_runtime.h>
#include <cstdint>
#include <cstddef>

#define FMIN_F (-3.402823466e38f)

__device__ __forceinline__ float wave_sum(float v) {
#pragma unroll
    for (int off = 32; off > 0; off >>= 1)
        v += __shfl_down(v, off, 64);
    return v; // valid in lane 0
}

// ---------------- GEMV: contiguous-walk ----------------
// R8 post-mortem: VGPR=64 + 236MB of scratch WRITE_SIZE -> w[8] spilled.
// R3..R8 invariant: every "waves own rows" shape streams at ~2.4 TB/s;
// proven-fast kernels (copy 6.3, RMSNorm 4.9 TB/s) walk CONTIGUOUS windows.
// This kernel copies that pattern: block owns 16 consecutive rows (256KB)
// and reads them front-to-back in 4KB whole-block requests (one row per
// iteration, all 256 threads contiguous). Thread's X column is fixed per
// quarter -> 16 float4 X in regs loaded once. Per row: 4 wave_sums + LDS
// partial; block emits final biased output rows (no K-split, no reduce
// kernel). Explicit 2-row double buffer wA/wB caps in-flight regs at 32
// (under the spill cliff), dynamic outer loop prevents unroll ballooning.
template <int NMAT>
__global__ __launch_bounds__(256, 2) void gemv_cw_kernel(
    const float* __restrict__ X,                                  // [4][4096]
    const float* __restrict__ W0, const float* __restrict__ B0,
    const float* __restrict__ W1, const float* __restrict__ B1,
    const float* __restrict__ W2, const float* __restrict__ B2,
    float scale0,
    float* __restrict__ Y)                                        // [NMAT*4][4096]
{
    const int tid  = threadIdx.x;
    const int wave = tid >> 6;
    const int lane = tid & 63;
    const int bid  = blockIdx.x;
    const int mi      = (NMAT == 1) ? 0 : (bid >> 8);
    const int rowbase = ((NMAT == 1) ? bid : (bid & 255)) * 16;

    const float* W  = (mi == 0) ? W0 : (mi == 1) ? W1 : W2;
    const float* Bs = (mi == 0) ? B0 : (mi == 1) ? B1 : B2;
    const float4* W4 = (const float4*)W + (size_t)rowbase * 1024;
    const float4* X4 = (const float4*)X;

    // X: this thread's fixed column per quarter, all 4 batches (16 float4).
    float4 xq[4][4];                              // [quarter][batch]
#pragma unroll
    for (int q = 0; q < 4; ++q)
#pragma unroll
        for (int b = 0; b < 4; ++b)
            xq[q][b] = X4[b * 1024 + q * 256 + tid];

    __shared__ float s_part[16][4][4];            // [row][wave][batch]

    float4 wA[4], wB[4];
#pragma unroll
    for (int q = 0; q < 4; ++q) wA[q] = W4[q * 256 + tid];      // row 0

#pragma unroll 1
    for (int r2 = 0; r2 < 8; ++r2) {
        const int r0 = 2 * r2;
        // prefetch row r0+1 into wB while computing row r0 from wA
#pragma unroll
        for (int q = 0; q < 4; ++q)
            wB[q] = W4[(size_t)(r0 + 1) * 1024 + q * 256 + tid];
        {
            float a0 = 0.f, a1 = 0.f, a2 = 0.f, a3 = 0.f;
#pragma unroll
            for (int q = 0; q < 4; ++q) {
                const float4 w = wA[q];
                a0 += w.x * xq[q][0].x + w.y * xq[q][0].y + w.z * xq[q][0].z + w.w * xq[q][0].w;
                a1 += w.x * xq[q][1].x + w.y * xq[q][1].y + w.z * xq[q][1].z + w.w * xq[q][1].w;
                a2 += w.x * xq[q][2].x + w.y * xq[q][2].y + w.z * xq[q][2].z + w.w * xq[q][2].w;
                a3 += w.x * xq[q][3].x + w.y * xq[q][3].y + w.z * xq[q][3].z + w.w * xq[q][3].w;
            }
            a0 = wave_sum(a0); a1 = wave_sum(a1);
            a2 = wave_sum(a2); a3 = wave_sum(a3);
            if (lane == 0) {
                s_part[r0][wave][0] = a0; s_part[r0][wave][1] = a1;
                s_part[r0][wave][2] = a2; s_part[r0][wave][3] = a3;
            }
        }
        // prefetch row (r0+2)&15 into wA (wraps at block end; in-bounds)
#pragma unroll
        for (int q = 0; q < 4; ++q)
            wA[q] = W4[(size_t)((r0 + 2) & 15) * 1024 + q * 256 + tid];
        {
            float a0 = 0.f, a1 = 0.f, a2 = 0.f, a3 = 0.f;
#pragma unroll
            for (int q = 0; q < 4; ++q) {
                const float4 w = wB[q];
                a0 += w.x * xq[q][0].x + w.y * xq[q][0].y + w.z * xq[q][0].z + w.w * xq[q][0].w;
                a1 += w.x * xq[q][1].x + w.y * xq[q][1].y + w.z * xq[q][1].z + w.w * xq[q][1].w;
                a2 += w.x * xq[q][2].x + w.y * xq[q][2].y + w.z * xq[q][2].z + w.w * xq[q][2].w;
                a3 += w.x * xq[q][3].x + w.y * xq[q][3].y + w.z * xq[q][3].z + w.w * xq[q][3].w;
            }
            a0 = wave_sum(a0); a1 = wave_sum(a1);
            a2 = wave_sum(a2); a3 = wave_sum(a3);
            if (lane == 0) {
                s_part[r0 + 1][wave][0] = a0; s_part[r0 + 1][wave][1] = a1;
                s_part[r0 + 1][wave][2] = a2; s_part[r0 + 1][wave][3] = a3;
            }
        }
    }
    __syncthreads();
    if (tid < 64) {
        const int r = tid >> 2, b = tid & 3;
        float s = s_part[r][0][b] + s_part[r][1][b]
                + s_part[r][2][b] + s_part[r][3][b];
        s += Bs[rowbase + r];
        if (mi == 0) s *= scale0;
        Y[((size_t)(mi * 4 + b)) * 4096 + rowbase + r] = s;
    }
}

// ---------------- Attention phase 1: scores ----------------
__global__ __launch_bounds__(256) void score_kernel(
    const float* __restrict__ qkv,     // [3][4][4096]
    const float* __restrict__ pk,      // [B,H,2048,128]
    const float* __restrict__ amask,   // [B,1,1,2049]
    const float* __restrict__ cam,     // [B*H,1,2049]
    const int* __restrict__ sbp, const int* __restrict__ rbp,
    float* __restrict__ scores)        // [128][512]
{
    constexpr int PAST = 2048, S = 2049, HD = 128;
    const int bh = blockIdx.y;
    const int b  = bh >> 5;
    const int h  = bh & 31;
    const int SB = sbp[0], RB = rbp[0];
    const int NS = SB + 1;
    const int NA = NS + RB + 1;

    const int wave = threadIdx.x >> 6;
    const int lane = threadIdx.x & 63;

    const float* qh   = qkv + (size_t)b * 4096 + h * HD;
    const float* knew = qkv + (size_t)(4 + b) * 4096 + h * HD;
    const float2 ql = ((const float2*)qh)[lane];

#pragma unroll
    for (int j = 0; j < 8; ++j) {
        const int i = blockIdx.x * 32 + j * 4 + wave;
        if (i >= NA) continue;
        const int s = (i < NS) ? i : (PAST - RB + (i - NS));
        const float2* kr = (s < PAST)
            ? (const float2*)(pk + ((size_t)bh * PAST + s) * HD)
            : (const float2*)knew;
        const float2 kk = kr[lane];
        float p = ql.x * kk.x + ql.y * kk.y;
        p = wave_sum(p);
        if (lane == 0) {
            const float m  = cam[(size_t)bh * S + s];
            float sc = fmaxf(p + amask[(size_t)b * S + s], FMIN_F);
            sc = sc * m + (1.0f - m) * FMIN_F;
            scores[(size_t)bh * 512 + i] = sc;
        }
    }
}

// ---------------- Attention phase 2: softmax + coefficient fixups ----------------
__global__ __launch_bounds__(256) void softmax_kernel(
    const float* __restrict__ ps,      // [B*H,2048]
    const int* __restrict__ sbp, const int* __restrict__ rbp,
    float* __restrict__ scores)        // [128][512] in/out
{
    constexpr int PAST = 2048;
    const int bh = blockIdx.x;
    const int SB = sbp[0], RB = rbp[0];
    const int NS = SB + 1;
    const int NA = NS + RB + 1;
    const int tid = threadIdx.x;

    __shared__ float s_c[512];
    __shared__ float s_red[256];
    __shared__ float s_mm;

    for (int i = tid; i < NA; i += 256) s_c[i] = scores[(size_t)bh * 512 + i];

    {
        float part = 0.0f;
        const int cnt = SB + RB;
        for (int i = tid; i < cnt; i += 256) {
            const int idx = (i < SB) ? i : (PAST - RB + (i - SB));
            part += ps[(size_t)bh * PAST + idx];
        }
        s_red[tid] = part;
    }
    __syncthreads();
#pragma unroll
    for (int st = 128; st > 0; st >>= 1) {
        if (tid < st) s_red[tid] += s_red[tid + st];
        __syncthreads();
    }
    if (tid == 0) {
        const float mean = s_red[0] / (float)(SB + RB);
        const float prob = ps[(size_t)bh * PAST + (PAST - RB)] / mean;
        s_mm = (prob > 1.0f) ? (1.0f / 32.0f) : 0.0f;
    }
    __syncthreads();

    float mx = -INFINITY;
    for (int i = tid; i < NA; i += 256) mx = fmaxf(mx, s_c[i]);
    s_red[tid] = mx;
    __syncthreads();
#pragma unroll
    for (int st = 128; st > 0; st >>= 1) {
        if (tid < st) s_red[tid] = fmaxf(s_red[tid], s_red[tid + st]);
        __syncthreads();
    }
    const float gmax = s_red[0];
    __syncthreads();

    float lsum = 0.0f;
    for (int i = tid; i < NA; i += 256) {
        const float e = expf(s_c[i] - gmax);
        s_c[i] = e;
        lsum += e;
    }
    s_red[tid] = lsum;
    __syncthreads();
#pragma unroll
    for (int st = 128; st > 0; st >>= 1) {
        if (tid < st) s_red[tid] += s_red[tid + st];
        __syncthreads();
    }
    const float inv = 1.0f / s_red[0];
    __syncthreads();
    for (int i = tid; i < NA; i += 256) s_c[i] *= inv;
    __syncthreads();

    if (tid == 0) {
        float sm = 0.0f;
#pragma unroll
        for (int j = 1; j <= 32; ++j) sm += s_c[NS + j];
        s_c[NS] += s_mm * sm;       // folded CAM value-merge
        s_c[SB]  = 0.99f;           // pinned col * 0.99 value scale
    }
    __syncthreads();

    for (int i = tid; i < NA; i += 256) scores[(size_t)bh * 512 + i] = s_c[i];
}

// ---------------- Attention phase 3: PV partials ----------------
__global__ __launch_bounds__(256) void pv_kernel(
    const float* __restrict__ qkv,     // for v_new
    const float* __restrict__ pv,      // [B,H,2048,128]
    const float* __restrict__ coeff,   // [128][512]
    const int* __restrict__ sbp, const int* __restrict__ rbp,
    float* __restrict__ partial)       // [128][8][128]
{
    constexpr int PAST = 2048, HD = 128;
    const int bh = blockIdx.y;
    const int b  = bh >> 5;
    const int h  = bh & 31;
    const int SB = sbp[0], RB = rbp[0];
    const int NS = SB + 1;
    const int NA = NS + RB + 1;
    const int CPC = (NA + 7) >> 3;
    const int i0 = blockIdx.x * CPC;
    const int i1 = min(NA, i0 + CPC);

    const int tid  = threadIdx.x;
    const int d    = tid & 127;
    const int half = tid >> 7;

    __shared__ float s_co[64];
    __shared__ float s_red[256];

    if (tid < i1 - i0) s_co[tid] = coeff[(size_t)bh * 512 + i0 + tid];
    __syncthreads();

    const float* vnew = qkv + (size_t)(8 + b) * 4096 + h * HD;

    float acc = 0.0f;
    for (int i = i0 + half; i < i1; i += 2) {
        const int s = (i < NS) ? i : (PAST - RB + (i - NS));
        const float* vr = (s < PAST)
            ? (pv + ((size_t)bh * PAST + s) * HD)
            : vnew;
        acc += s_co[i - i0] * vr[d];
    }
    s_red[tid] = acc;
    __syncthreads();
    if (tid < 128)
        partial[((size_t)bh * 8 + blockIdx.x) * HD + d] = s_red[tid] + s_red[tid + 128];
}

// ---------------- Attention phase 4: reduce partials ----------------
__global__ __launch_bounds__(256) void attn_reduce_kernel(
    const float* __restrict__ partial,  // [128][8][128]
    float* __restrict__ attn_out)       // [4][4096] == [128][128]
{
    const int idx = blockIdx.x * 256 + threadIdx.x;
    const int bh = idx >> 7;
    const int d  = idx & 127;
    float s = 0.0f;
#pragma unroll
    for (int c = 0; c < 8; ++c)
        s += partial[(size_t)bh * 1024 + c * 128 + d];
    attn_out[idx] = s;
}

extern "C" void kernel_launch(void* const* d_in, const int* in_sizes, int n_in,
                              void* d_out, int out_size, void* d_ws, size_t ws_size,
                              hipStream_t stream)
{
    const float* hs = (const float*)d_in[0];
    const float* pk = (const float*)d_in[1];
    const float* pv = (const float*)d_in[2];
    const float* am = (const float*)d_in[3];
    const float* cm = (const float*)d_in[4];
    const float* ps = (const float*)d_in[5];
    const float* Wq = (const float*)d_in[6];
    const float* bq = (const float*)d_in[7];
    const float* Wk = (const float*)d_in[8];
    const float* bk = (const float*)d_in[9];
    const float* Wv = (const float*)d_in[10];
    const float* bv = (const float*)d_in[11];
    const float* Wo = (const float*)d_in[12];
    const float* bo = (const float*)d_in[13];
    const int*   sb = (const int*)d_in[14];
    const int*   rb = (const int*)d_in[15];

    float* qkv  = (float*)d_ws;                 // 3*4*4096 = 49152
    float* aout = qkv + 3 * 4 * 4096;           // 16384
    float* sc   = aout + 4 * 4096;              // 65536
    float* part = sc + 128 * 512;               // 131072
    float* out  = (float*)d_out;

    const float scaling = 0.08838834764831845f;  // 128^-0.5

    gemv_cw_kernel<3><<<768, 256, 0, stream>>>(hs, Wq, bq, Wk, bk, Wv, bv, scaling, qkv);
    score_kernel<<<dim3(16, 128), 256, 0, stream>>>(qkv, pk, am, cm, sb, rb, sc);
    softmax_kernel<<<128, 256, 0, stream>>>(ps, sb, rb, sc);
    pv_kernel<<<dim3(8, 128), 256, 0, stream>>>(qkv, pv, sc, sb, rb, part);
    attn_reduce_kernel<<<64, 256, 0, stream>>>(part, aout);
    gemv_cw_kernel<1><<<256, 256, 0, stream>>>(aout, Wo, bo, Wo, bo, Wo, bo, 1.0f, out);
}